// Round 1
// baseline (188.686 us; speedup 1.0000x reference)
//
#include <hip/hip_runtime.h>
#include <math.h>

// Top-8 (sorted desc) along last axis of (1024, 256, 128) fp32.
// 4 lanes cooperate per row. Persistent grid: 2048 blocks (8/CU x 256 CU,
// exact residency fill), each block walks 2 chunks of 64 rows.
// Per chunk: 8x global_load_dwordx4 (128 B/lane in flight), med3
// sorted-insert of 32 elements/lane, then 2 shuffle-butterfly merge
// stages (masks 1,2) via the bitonic halver + 12-CE merge.
// Cross-chunk register prefetch: v[8] is dead after the INS phase, so the
// next chunk's 8 loads are issued into the same 32 VGPRs BEFORE the
// merge+store of the current chunk -- next-chunk HBM latency hides under
// merge/store VALU with zero extra register pressure (stay under the
// 64-VGPR occupancy cliff). No LDS, no barriers.

#define NC    128
#define TPB   256
#define NBLK  2048   // 8 blocks/CU * 256 CU = exact residency fill

__device__ __forceinline__ float med3f(float a, float b, float c) {
    return __builtin_amdgcn_fmed3f(a, b, c);
}

// compare-exchange, descending: a keeps max, b keeps min
#define CE(a, b) do { float _t = fmaxf(a, b); b = fminf(a, b); a = _t; } while (0)

#define INS(v) do {                          \
    float n0 = fmaxf(s0, (v));               \
    float n1 = med3f(s0, s1, (v));           \
    float n2 = med3f(s1, s2, (v));           \
    float n3 = med3f(s2, s3, (v));           \
    float n4 = med3f(s3, s4, (v));           \
    float n5 = med3f(s4, s5, (v));           \
    float n6 = med3f(s5, s6, (v));           \
    float n7 = med3f(s6, s7, (v));           \
    s0 = n0; s1 = n1; s2 = n2; s3 = n3;      \
    s4 = n4; s5 = n5; s6 = n6; s7 = n7;      \
} while (0)

__global__ __launch_bounds__(TPB) void topk8_kernel(const float* __restrict__ x,
                                                    float* __restrict__ out,
                                                    int nchunks) {
    const int lane = threadIdx.x & 63;
    const int s    = lane & 3;     // sub-lane within the 4-lane row group
    const int g    = lane >> 2;    // row group within wave (0..15)
    const int w    = threadIdx.x >> 6;                 // wave in block
    const int rc   = w * 16 + g;                       // row within 64-row chunk

    long chunk = blockIdx.x;
    // lane's base: row start + 4*s elements; loads at +16*j elements (64 B)
    const float* __restrict__ xp = x + (chunk * 64 + rc) * (long)NC + 4 * s;
    float*       __restrict__ op = out + (chunk * 64 + rc) * 8 + 2 * s;

    const long xstep = (long)NBLK * 64 * NC;  // elements per chunk stride
    const long ostep = (long)NBLK * 64 * 8;

    // prologue: loads for first chunk. Per instruction the wave covers one
    // 64-B line per row x 16 rows; across j=0..7 a contiguous 8-KiB span.
    float4 v[8];
    #pragma unroll
    for (int j = 0; j < 8; ++j)
        v[j] = *reinterpret_cast<const float4*>(xp + 16 * j);

    for (;;) {
        float s0 = -INFINITY, s1 = -INFINITY, s2 = -INFINITY, s3 = -INFINITY;
        float s4 = -INFINITY, s5 = -INFINITY, s6 = -INFINITY, s7 = -INFINITY;

        #pragma unroll
        for (int j = 0; j < 8; ++j) {
            INS(v[j].x); INS(v[j].y); INS(v[j].z); INS(v[j].w);
        }

        // v[] is dead now: prefetch next chunk into the same registers
        // before doing the merge network + store of the current chunk.
        chunk += NBLK;
        const bool more = chunk < nchunks;   // wave-uniform branch
        if (more) {
            xp += xstep;
            #pragma unroll
            for (int j = 0; j < 8; ++j)
                v[j] = *reinterpret_cast<const float4*>(xp + 16 * j);
        }

        // 2 butterfly stages (masks 1,2 stay inside the 4-lane group).
        #pragma unroll
        for (int m = 1; m <= 2; m <<= 1) {
            const float b0 = __shfl_xor(s0, m);
            const float b1 = __shfl_xor(s1, m);
            const float b2 = __shfl_xor(s2, m);
            const float b3 = __shfl_xor(s3, m);
            const float b4 = __shfl_xor(s4, m);
            const float b5 = __shfl_xor(s5, m);
            const float b6 = __shfl_xor(s6, m);
            const float b7 = __shfl_xor(s7, m);
            // halver: top-8 of union (result bitonic)
            float t0 = fmaxf(s0, b7), t1 = fmaxf(s1, b6);
            float t2 = fmaxf(s2, b5), t3 = fmaxf(s3, b4);
            float t4 = fmaxf(s4, b3), t5 = fmaxf(s5, b2);
            float t6 = fmaxf(s6, b1), t7 = fmaxf(s7, b0);
            // bitonic merge network, descending
            CE(t0, t4); CE(t1, t5); CE(t2, t6); CE(t3, t7);
            CE(t0, t2); CE(t1, t3); CE(t4, t6); CE(t5, t7);
            CE(t0, t1); CE(t2, t3); CE(t4, t5); CE(t6, t7);
            s0 = t0; s1 = t1; s2 = t2; s3 = t3;
            s4 = t4; s5 = t5; s6 = t6; s7 = t7;
        }

        // All 4 lanes hold the full sorted list; lane s stores elements
        // {2s, 2s+1} as one float2 -> 32 B contiguous per row.
        const float r0 = s == 0 ? s0 : s == 1 ? s2 : s == 2 ? s4 : s6;
        const float r1 = s == 0 ? s1 : s == 1 ? s3 : s == 2 ? s5 : s7;
        *reinterpret_cast<float2*>(op) = make_float2(r0, r1);

        if (!more) break;
        op += ostep;
    }
}

extern "C" void kernel_launch(void* const* d_in, const int* in_sizes, int n_in,
                              void* d_out, int out_size, void* d_ws, size_t ws_size,
                              hipStream_t stream) {
    const float* x = (const float*)d_in[0];
    float* out     = (float*)d_out;
    const long total  = (long)in_sizes[0];   // 1024*256*128
    const int  nrows  = (int)(total / NC);   // 262144
    const int  nchunks = nrows / 64;         // 4096 chunks of 64 rows
    const int  blocks  = nchunks < NBLK ? nchunks : NBLK;
    topk8_kernel<<<blocks, TPB, 0, stream>>>(x, out, nchunks);
}